// Round 7
// baseline (7222.353 us; speedup 1.0000x reference)
//
#include <hip/hip_runtime.h>
#include <hip/hip_bf16.h>
#include <math.h>

typedef float in_t;
typedef float out_t;

__device__ __forceinline__ float ldi(const in_t* p, size_t i) { return (float)p[i]; }

#define DMODEL 192
#define NTOK   197
#define BT_    80
#define ROWS_  (BT_*NTOK)   // 15760

__device__ __forceinline__ float gelu_f(float v) {
  return 0.5f*v*(1.f + tanhf(0.7978845608028654f*(v + 0.044715f*v*v*v)));
}

// ================= GEMM A (round-2 measured): 64x64, 4x4/thread ===========
// Both operands staged in LDS. EPI: 0=bias, 1=bias+gelu, 2=bias+residual(R)
template<int EPI>
__global__ __launch_bounds__(256)
void gemmA_k(const float* __restrict__ A, const in_t* __restrict__ W,
             const in_t* __restrict__ bias, const float* __restrict__ R,
             float* __restrict__ C, int M, int N, int K)
{
  constexpr int BM=64, BN=64, BK=16;
  __shared__ float As[BK][BM+4];
  __shared__ float Ws[BK][BN+4];
  const int t = threadIdx.x;
  const int bm0 = blockIdx.y*BM, bn0 = blockIdx.x*BN;
  const int tm = (t>>4)*4;
  const int tn = (t&15)*4;
  const int la_m = t>>2;
  const int la_k = (t&3)*4;
  const int lw_k = t>>4;
  const int lw_n = (t&15)*4;
  float acc[4][4] = {};
  for (int k0 = 0; k0 < K; k0 += BK) {
    int gm = bm0 + la_m;
    float4 av = make_float4(0.f,0.f,0.f,0.f);
    if (gm < M) av = *(const float4*)(A + (size_t)gm*K + (size_t)(k0 + la_k));
    As[la_k+0][la_m] = av.x; As[la_k+1][la_m] = av.y;
    As[la_k+2][la_m] = av.z; As[la_k+3][la_m] = av.w;
    const in_t* wp = W + (size_t)(k0+lw_k)*N + (size_t)(bn0+lw_n);
    Ws[lw_k][lw_n+0] = ldi(wp,0); Ws[lw_k][lw_n+1] = ldi(wp,1);
    Ws[lw_k][lw_n+2] = ldi(wp,2); Ws[lw_k][lw_n+3] = ldi(wp,3);
    __syncthreads();
    #pragma unroll
    for (int kk=0; kk<BK; ++kk) {
      float4 a4 = *(const float4*)&As[kk][tm];
      float4 b4 = *(const float4*)&Ws[kk][tn];
      float ar[4] = {a4.x,a4.y,a4.z,a4.w};
      float br[4] = {b4.x,b4.y,b4.z,b4.w};
      #pragma unroll
      for (int ii=0; ii<4; ++ii)
        #pragma unroll
        for (int jj=0; jj<4; ++jj)
          acc[ii][jj] = fmaf(ar[ii], br[jj], acc[ii][jj]);
    }
    __syncthreads();
  }
  #pragma unroll
  for (int ii=0; ii<4; ++ii) {
    int gm = bm0 + tm + ii;
    if (gm >= M) continue;
    int gn = bn0 + tn;
    float v0=acc[ii][0], v1=acc[ii][1], v2=acc[ii][2], v3=acc[ii][3];
    if (bias) { v0+=ldi(bias,gn); v1+=ldi(bias,gn+1); v2+=ldi(bias,gn+2); v3+=ldi(bias,gn+3); }
    if (EPI==1) { v0=gelu_f(v0); v1=gelu_f(v1); v2=gelu_f(v2); v3=gelu_f(v3); }
    if (EPI==2) {
      const float4 r4 = *(const float4*)(R + (size_t)gm*N + gn);
      v0+=r4.x; v1+=r4.y; v2+=r4.z; v3+=r4.w;
    }
    *(float4*)(C + (size_t)gm*N + gn) = make_float4(v0,v1,v2,v3);
  }
}

// ================= GEMM B: 128x64, 8x8/thread, 128 threads ================
// Both operands in LDS. 4 b128 LDS reads per 64 FMA -> LDS demand 1.5x
// (vs 3x for 4x4) -> ~2x GEMM throughput where the grid is wide enough.
// Use only for N >= 576 (grid >= 1100 blocks).
template<int EPI>
__global__ __launch_bounds__(128)
void gemmB_k(const float* __restrict__ A, const in_t* __restrict__ W,
             const in_t* __restrict__ bias, const float* __restrict__ R,
             float* __restrict__ C, int M, int N, int K)
{
  constexpr int BM=128, BN=64, BK=16;
  __shared__ float As[BK][BM+4];
  __shared__ float Ws[BK][BN+4];
  const int t = threadIdx.x;
  const int bm0 = blockIdx.y*BM, bn0 = blockIdx.x*BN;
  const int tm = (t>>3)*8;      // 0..120
  const int tn = (t&7)*8;       // 0..56
  float acc[8][8] = {};
  for (int k0 = 0; k0 < K; k0 += BK) {
    // stage A: 128x16 floats, 4 float4 loads/thread
    #pragma unroll
    for (int u = 0; u < 4; ++u) {
      int fidx = t + u*128;           // 0..511
      int row = fidx >> 2;            // 0..127
      int kq  = (fidx & 3)*4;         // 0,4,8,12
      int gm = bm0 + row;
      float4 av = make_float4(0.f,0.f,0.f,0.f);
      if (gm < M) av = *(const float4*)(A + (size_t)gm*K + (size_t)(k0 + kq));
      As[kq+0][row] = av.x; As[kq+1][row] = av.y;
      As[kq+2][row] = av.z; As[kq+3][row] = av.w;
    }
    // stage W: 16x64 floats, 2 float4 loads/thread
    #pragma unroll
    for (int u = 0; u < 2; ++u) {
      int idx = t + u*128;            // 0..255
      int lw_k = idx >> 4;            // 0..15
      int lw_n = (idx & 15)*4;        // 0..60
      const in_t* wp = W + (size_t)(k0+lw_k)*N + (size_t)(bn0+lw_n);
      float4 wv = make_float4(ldi(wp,0), ldi(wp,1), ldi(wp,2), ldi(wp,3));
      *(float4*)&Ws[lw_k][lw_n] = wv;
    }
    __syncthreads();
    #pragma unroll
    for (int kk = 0; kk < BK; ++kk) {
      float4 a0 = *(const float4*)&As[kk][tm];
      float4 a1 = *(const float4*)&As[kk][tm+4];
      float4 w0 = *(const float4*)&Ws[kk][tn];
      float4 w1 = *(const float4*)&Ws[kk][tn+4];
      float ar[8] = {a0.x,a0.y,a0.z,a0.w,a1.x,a1.y,a1.z,a1.w};
      float wr[8] = {w0.x,w0.y,w0.z,w0.w,w1.x,w1.y,w1.z,w1.w};
      #pragma unroll
      for (int ii=0; ii<8; ++ii)
        #pragma unroll
        for (int jj=0; jj<8; ++jj)
          acc[ii][jj] = fmaf(ar[ii], wr[jj], acc[ii][jj]);
    }
    __syncthreads();
  }
  #pragma unroll
  for (int ii=0; ii<8; ++ii) {
    int gm = bm0 + tm + ii;
    if (gm >= M) continue;
    int gn = bn0 + tn;
    float v[8];
    #pragma unroll
    for (int jj=0; jj<8; ++jj) {
      v[jj] = acc[ii][jj];
      if (bias) v[jj] += ldi(bias, gn+jj);
      if (EPI==1) v[jj] = gelu_f(v[jj]);
    }
    if (EPI==2) {
      const float4 r0 = *(const float4*)(R + (size_t)gm*N + gn);
      const float4 r1 = *(const float4*)(R + (size_t)gm*N + gn + 4);
      v[0]+=r0.x; v[1]+=r0.y; v[2]+=r0.z; v[3]+=r0.w;
      v[4]+=r1.x; v[5]+=r1.y; v[6]+=r1.z; v[7]+=r1.w;
    }
    *(float4*)(C + (size_t)gm*N + gn)     = make_float4(v[0],v[1],v[2],v[3]);
    *(float4*)(C + (size_t)gm*N + gn + 4) = make_float4(v[4],v[5],v[6],v[7]);
  }
}

// ================= LayerNorm over width 192 =================
__global__ __launch_bounds__(256)
void ln_k(const float* __restrict__ x, const in_t* __restrict__ g, const in_t* __restrict__ b,
          float* __restrict__ o, int rows)
{
  int t = threadIdx.x, wave = t>>6, lane = t&63;
  int r = blockIdx.x*4 + wave;
  if (r >= rows) return;
  const float* xr = x + (size_t)r*DMODEL;
  float e0 = xr[lane], e1 = xr[lane+64], e2 = xr[lane+128];
  float s = e0+e1+e2;
  #pragma unroll
  for (int off=32; off; off>>=1) s += __shfl_xor(s, off);
  float mean = s / 192.f;
  float d0=e0-mean, d1=e1-mean, d2=e2-mean;
  float v = d0*d0+d1*d1+d2*d2;
  #pragma unroll
  for (int off=32; off; off>>=1) v += __shfl_xor(v, off);
  float rs = 1.f / sqrtf(v/192.f + 1e-6f);
  float* orow = o + (size_t)r*DMODEL;
  orow[lane]     = d0*rs*ldi(g,lane)     + ldi(b,lane);
  orow[lane+64]  = d1*rs*ldi(g,lane+64)  + ldi(b,lane+64);
  orow[lane+128] = d2*rs*ldi(g,lane+128) + ldi(b,lane+128);
}

// ================= Fused attention v2 (round-2 measured) ==================
template<int DH, int W>
__global__ __launch_bounds__(W*64)
void attn2_k(const float* __restrict__ qkv, float* __restrict__ out,
             float* __restrict__ attn0, int Nseq, int heads, float scale)
{
  constexpr int QT = 8;
  constexpr int KTS = 204;
  constexpr int NPARTS = 64 / DH;
  __shared__ float Kt[DH * KTS];
  __shared__ float Qt[W][DH][12];
  __shared__ float Ps[W][QT][200];

  const int bh = blockIdx.x;
  const int b = bh / heads, h = bh % heads;
  const int stride = 3 * heads * DH;
  const float* __restrict__ base = qkv + (size_t)b * Nseq * stride;
  const int qo = h * DH, ko = heads * DH + h * DH, vo = 2 * heads * DH + h * DH;
  const int t = threadIdx.x, w = t >> 6, lane = t & 63;

  for (int idx = t; idx < Nseq * DH; idx += W * 64) {
    int j = idx / DH, d0 = idx - j * DH;
    Kt[d0 * KTS + j] = base[(size_t)j * stride + ko + d0];
  }
  __syncthreads();

  const int d = lane & (DH - 1);
  const int part = (DH == 64) ? 0 : (lane >> 5);
  const int nchunks = (Nseq + QT - 1) / QT;
  const int jcmax = (Nseq + 3) >> 2;
  const float NEG = -3.0e38f;
  const float4* Kt4 = (const float4*)Kt;

  for (int ic = w; ic < nchunks; ic += W) {
    const int i0 = ic * QT;
    if (part == 0) {
      #pragma unroll
      for (int q = 0; q < QT; ++q) {
        int i = i0 + q;
        Qt[w][d][q] = (i < Nseq) ? base[(size_t)i * stride + qo + d] : 0.f;
      }
    }
    float s[QT][4];
    #pragma unroll
    for (int q = 0; q < QT; ++q)
      #pragma unroll
      for (int u = 0; u < 4; ++u) s[q][u] = 0.f;
    #pragma unroll 4
    for (int dd = 0; dd < DH; ++dd) {
      float4 kv = (lane < 51) ? Kt4[dd * (KTS/4) + lane] : make_float4(0.f,0.f,0.f,0.f);
      float4 qA = *(const float4*)&Qt[w][dd][0];
      float4 qB = *(const float4*)&Qt[w][dd][4];
      float qv[8] = {qA.x, qA.y, qA.z, qA.w, qB.x, qB.y, qB.z, qB.w};
      float kr[4] = {kv.x, kv.y, kv.z, kv.w};
      #pragma unroll
      for (int q = 0; q < QT; ++q)
        #pragma unroll
        for (int u = 0; u < 4; ++u)
          s[q][u] = fmaf(qv[q], kr[u], s[q][u]);
    }
    float inv[QT];
    #pragma unroll
    for (int q = 0; q < QT; ++q) {
      float mx = NEG;
      #pragma unroll
      for (int u = 0; u < 4; ++u) {
        int j = 4*lane + u;
        s[q][u] = (j < Nseq) ? s[q][u]*scale : NEG;
        mx = fmaxf(mx, s[q][u]);
      }
      #pragma unroll
      for (int off = 32; off; off >>= 1) mx = fmaxf(mx, __shfl_xor(mx, off));
      float sum = 0.f;
      #pragma unroll
      for (int u = 0; u < 4; ++u) {
        float p = (4*lane + u < Nseq) ? expf(s[q][u] - mx) : 0.f;
        s[q][u] = p; sum += p;
      }
      #pragma unroll
      for (int off = 32; off; off >>= 1) sum += __shfl_xor(sum, off);
      inv[q] = 1.f / sum;
      if (lane < 50)
        *(float4*)&Ps[w][q][4*lane] = make_float4(s[q][0], s[q][1], s[q][2], s[q][3]);
    }
    if (attn0 != nullptr && i0 == 0) {
      #pragma unroll
      for (int u = 0; u < 4; ++u) {
        int j = 4*lane + u;
        if (j < Nseq) attn0[(size_t)bh*Nseq + j] = s[0][u]*inv[0];
      }
    }
    float o[QT];
    #pragma unroll
    for (int q = 0; q < QT; ++q) o[q] = 0.f;
    const float* __restrict__ Vg = base + vo;
    for (int jc = part; jc < jcmax; jc += NPARTS) {
      int jb = 4*jc;
      float v0 = (jb+0 < Nseq) ? Vg[(size_t)(jb+0)*stride + d] : 0.f;
      float v1 = (jb+1 < Nseq) ? Vg[(size_t)(jb+1)*stride + d] : 0.f;
      float v2 = (jb+2 < Nseq) ? Vg[(size_t)(jb+2)*stride + d] : 0.f;
      float v3 = (jb+3 < Nseq) ? Vg[(size_t)(jb+3)*stride + d] : 0.f;
      #pragma unroll
      for (int q = 0; q < QT; ++q) {
        float4 pq = *(const float4*)&Ps[w][q][jb];
        o[q] = fmaf(pq.w, v3, fmaf(pq.z, v2, fmaf(pq.y, v1, fmaf(pq.x, v0, o[q]))));
      }
    }
    if (NPARTS == 2) {
      #pragma unroll
      for (int q = 0; q < QT; ++q) o[q] += __shfl_xor(o[q], 32);
    }
    #pragma unroll
    for (int q = 0; q < QT; ++q) {
      int i = i0 + q;
      if (i < Nseq && part == 0)
        out[((size_t)b*Nseq + i)*(size_t)(heads*DH) + h*DH + d] = o[q]*inv[q];
    }
  }
}

// ================= patch extraction =================
__global__ void patchify_k(const in_t* __restrict__ x, float* __restrict__ A)
{
  int idx = blockIdx.x*256 + threadIdx.x;
  const int total = BT_*196*768;
  if (idx >= total) return;
  int kc = idx % 768;
  int m  = idx / 768;
  int p  = m % 196;
  int bt = m / 196;
  int c  = kc >> 8;
  int py = (kc >> 4) & 15;
  int px = kc & 15;
  int ph = p / 14, pw = p % 14;
  size_t src = (((size_t)bt*3 + c)*224 + (ph*16+py))*224 + (pw*16+px);
  A[idx] = ldi(x, src);
}

// ================= assemble tokens =================
__global__ void assemble_k(const float* __restrict__ pt, const in_t* __restrict__ st,
                           const in_t* __restrict__ pe, float* __restrict__ X)
{
  int i = blockIdx.x*256 + threadIdx.x;
  const int total = BT_*NTOK*DMODEL;
  if (i >= total) return;
  int d  = i % DMODEL;
  int n  = (i / DMODEL) % NTOK;
  int bt = i / (DMODEL*NTOK);
  int tt = bt % 5;
  float base = (n == 0) ? ldi(st, d)
                        : pt[((size_t)bt*196 + (n-1))*DMODEL + d];
  X[i] = base + ldi(pe, ((size_t)tt*NTOK + n)*DMODEL + d);
}

// ================= ATS significance score =================
__global__ void score_k(const float* __restrict__ attn0, const float* __restrict__ qkv,
                        float* __restrict__ S)
{
  int b = blockIdx.x;
  int jj = threadIdx.x;
  if (jj >= 196) return;
  int j = jj + 1;
  float acc = 0.f;
  #pragma unroll
  for (int h = 0; h < 6; ++h) {
    float a0 = attn0[((size_t)b*6 + h)*NTOK + j];
    const float* v = qkv + ((size_t)b*NTOK + j)*576 + 384 + h*32;
    float ss = 0.f;
    #pragma unroll
    for (int d = 0; d < 32; ++d) ss += v[d]*v[d];
    acc += a0 * sqrtf(ss);
  }
  S[(size_t)b*196 + jj] = acc / 6.0f;
}

// ================= ATS sampling =================
__global__ void sample_k(const float* __restrict__ S, int* __restrict__ idxout)
{
  __shared__ float cdf[196];
  int b = blockIdx.x, t = threadIdx.x;
  if (t == 0) {
    float tot = 0.f;
    for (int k = 0; k < 196; ++k) tot += S[(size_t)b*196 + k];
    float denom = tot + 1e-8f;
    float run = 0.f;
    for (int k = 0; k < 196; ++k) { run += S[(size_t)b*196 + k] / denom; cdf[k] = run; }
    idxout[(size_t)b*NTOK] = 0;
  }
  __syncthreads();
  if (t < 196) {
    float u = ((float)t + 0.5f) / 196.0f;
    int cnt = 0;
    for (int k = 0; k < 196; ++k) cnt += (cdf[k] < u) ? 1 : 0;
    int c = cnt > 195 ? 195 : cnt;
    idxout[(size_t)b*NTOK + 1 + t] = c + 1;
  }
}

// ================= gather =================
__global__ void gather_k(const float* __restrict__ X, const float* __restrict__ P,
                         const int* __restrict__ idx, float* __restrict__ Xo)
{
  int i = blockIdx.x*256 + threadIdx.x;
  const int total = BT_*NTOK*DMODEL;
  if (i >= total) return;
  int d  = i % DMODEL;
  int n  = (i / DMODEL) % NTOK;
  int bt = i / (DMODEL*NTOK);
  int src = idx[(size_t)bt*NTOK + n];
  size_t sr = ((size_t)bt*NTOK + src)*DMODEL + d;
  Xo[i] = X[sr] + P[sr];
}

// ================= build temporal sequence =================
__global__ void build_xc_k(const float* __restrict__ X, const in_t* __restrict__ tt,
                           float* __restrict__ xc)
{
  int i = blockIdx.x*256 + threadIdx.x;
  const int total = 16*6*DMODEL;
  if (i >= total) return;
  int d = i % DMODEL;
  int n = (i / DMODEL) % 6;
  int b = i / (DMODEL*6);
  xc[i] = (n == 0) ? ldi(tt, d)
                   : X[(((size_t)b*5 + (n-1))*NTOK + 0)*DMODEL + d];
}

// ================= maxpool + final LN + MLP head =================
__global__ __launch_bounds__(256)
void head_k(const float* __restrict__ xc, const in_t* __restrict__ fg, const in_t* __restrict__ fb,
            const in_t* __restrict__ w1, const in_t* __restrict__ b1,
            const in_t* __restrict__ w2, const in_t* __restrict__ b2,
            out_t* __restrict__ outp)
{
  __shared__ float fn[DMODEL];
  __shared__ float hid[64];
  __shared__ float mv[2];
  int b = blockIdx.x, t = threadIdx.x;
  if (t < DMODEL) {
    float m = xc[((size_t)b*6 + 0)*DMODEL + t];
    #pragma unroll
    for (int n = 1; n < 6; ++n) m = fmaxf(m, xc[((size_t)b*6 + n)*DMODEL + t]);
    fn[t] = m;
  }
  __syncthreads();
  if (t == 0) {
    float s = 0.f;
    for (int d = 0; d < DMODEL; ++d) s += fn[d];
    float mean = s / 192.f;
    float v = 0.f;
    for (int d = 0; d < DMODEL; ++d) { float dd = fn[d]-mean; v += dd*dd; }
    mv[0] = mean; mv[1] = 1.f / sqrtf(v/192.f + 1e-6f);
  }
  __syncthreads();
  if (t < DMODEL) fn[t] = (fn[t]-mv[0])*mv[1]*ldi(fg,t) + ldi(fb,t);
  __syncthreads();
  if (t < 64) {
    float a = ldi(b1, t);
    for (int d = 0; d < DMODEL; ++d) a += fn[d]*ldi(w1, (size_t)d*64 + t);
    hid[t] = fmaxf(a, 0.f);
  }
  __syncthreads();
  if (t < 2) {
    float a = ldi(b2, t);
    for (int j = 0; j < 64; ++j) a += hid[j]*ldi(w2, (size_t)j*2 + t);
    outp[(size_t)b*2 + t] = (out_t)a;
  }
}

// =========================================================================
extern "C" void kernel_launch(void* const* d_in, const int* in_sizes, int n_in,
                              void* d_out, int out_size, void* d_ws, size_t ws_size,
                              hipStream_t stream)
{
  if (n_in < 50) return;
  const in_t* x_in     = (const in_t*)d_in[0];
  const in_t* patch_w  = (const in_t*)d_in[1];
  const in_t* patch_b  = (const in_t*)d_in[2];
  const in_t* pos_emb  = (const in_t*)d_in[3];
  const in_t* space_tk = (const in_t*)d_in[4];
  const in_t* temp_tk  = (const in_t*)d_in[5];
  const in_t* s_ln1_g = (const in_t*)d_in[6];  const in_t* s_ln1_b = (const in_t*)d_in[7];
  const in_t* s_qkv_w = (const in_t*)d_in[8];  const in_t* s_out_w = (const in_t*)d_in[9];
  const in_t* s_out_b = (const in_t*)d_in[10]; const in_t* s_ln2_g = (const in_t*)d_in[11];
  const in_t* s_ln2_b = (const in_t*)d_in[12]; const in_t* s_fc1_w = (const in_t*)d_in[13];
  const in_t* s_fc1_b = (const in_t*)d_in[14]; const in_t* s_fc2_w = (const in_t*)d_in[15];
  const in_t* s_fc2_b = (const in_t*)d_in[16]; const in_t* s_nrm_g = (const in_t*)d_in[17];
  const in_t* s_nrm_b = (const in_t*)d_in[18];
  const in_t* t_ln1_g = (const in_t*)d_in[19]; const in_t* t_ln1_b = (const in_t*)d_in[20];
  const in_t* t_qkv_w = (const in_t*)d_in[21]; const in_t* t_out_w = (const in_t*)d_in[22];
  const in_t* t_out_b = (const in_t*)d_in[23]; const in_t* t_ln2_g = (const in_t*)d_in[24];
  const in_t* t_ln2_b = (const in_t*)d_in[25]; const in_t* t_fc1_w = (const in_t*)d_in[26];
  const in_t* t_fc1_b = (const in_t*)d_in[27]; const in_t* t_fc2_w = (const in_t*)d_in[28];
  const in_t* t_fc2_b = (const in_t*)d_in[29]; const in_t* t_nrm_g = (const in_t*)d_in[30];
  const in_t* t_nrm_b = (const in_t*)d_in[31];
  const in_t* a_ln1_g = (const in_t*)d_in[32]; const in_t* a_ln1_b = (const in_t*)d_in[33];
  const in_t* a_qkv_w = (const in_t*)d_in[34]; const in_t* a_qkv_b = (const in_t*)d_in[35];
  const in_t* a_prj_w = (const in_t*)d_in[36]; const in_t* a_prj_b = (const in_t*)d_in[37];
  const in_t* a_ln2_g = (const in_t*)d_in[38]; const in_t* a_ln2_b = (const in_t*)d_in[39];
  const in_t* a_fc1_w = (const in_t*)d_in[40]; const in_t* a_fc1_b = (const in_t*)d_in[41];
  const in_t* a_fc2_w = (const in_t*)d_in[42]; const in_t* a_fc2_b = (const in_t*)d_in[43];
  const in_t* final_g = (const in_t*)d_in[44]; const in_t* final_b = (const in_t*)d_in[45];
  const in_t* h1_w = (const in_t*)d_in[46];    const in_t* h1_b = (const in_t*)d_in[47];
  const in_t* h2_w = (const in_t*)d_in[48];    const in_t* h2_b = (const in_t*)d_in[49];

  float* ws = (float*)d_ws;
  size_t off = 0;
  auto alloc = [&](size_t nf) { size_t r = off; off += (nf + 63) & ~((size_t)63); return r; };
  size_t oX   = alloc((size_t)ROWS_*DMODEL);
  size_t oX2  = alloc((size_t)ROWS_*DMODEL);
  size_t oH   = alloc((size_t)ROWS_*DMODEL);
  size_t oQKV = alloc((size_t)ROWS_*1152);
  size_t oY   = alloc((size_t)ROWS_*384);
  size_t oFF  = alloc((size_t)ROWS_*768);
  size_t oA0  = alloc((size_t)480*NTOK);
  size_t oSB  = alloc((size_t)BT_*196);
  size_t oXC  = alloc((size_t)16*6*DMODEL);
  size_t oIDX = alloc((size_t)BT_*NTOK);
  if (ws_size < off*sizeof(float)) return;

  float* X   = ws + oX;
  float* X2  = ws + oX2;
  float* H   = ws + oH;
  float* QKV = ws + oQKV;
  float* Y   = ws + oY;
  float* FF  = ws + oFF;
  float* A0  = ws + oA0;
  float* SB  = ws + oSB;
  float* XC  = ws + oXC;
  int*   IDX = (int*)(ws + oIDX);

  auto gemm = [&](int epi, const float* A, const in_t* W, const in_t* bias,
                  const float* R, float* C, int M, int N, int K) {
    if (N >= 576 && M >= 1024) {
      dim3 grid(N/64, (M+127)/128);
      if (epi == 0)      hipLaunchKernelGGL(gemmB_k<0>, grid, dim3(128), 0, stream, A, W, bias, R, C, M, N, K);
      else if (epi == 1) hipLaunchKernelGGL(gemmB_k<1>, grid, dim3(128), 0, stream, A, W, bias, R, C, M, N, K);
      else               hipLaunchKernelGGL(gemmB_k<2>, grid, dim3(128), 0, stream, A, W, bias, R, C, M, N, K);
    } else {
      dim3 grid(N/64, (M+63)/64);
      if (epi == 0)      hipLaunchKernelGGL(gemmA_k<0>, grid, dim3(256), 0, stream, A, W, bias, R, C, M, N, K);
      else if (epi == 1) hipLaunchKernelGGL(gemmA_k<1>, grid, dim3(256), 0, stream, A, W, bias, R, C, M, N, K);
      else               hipLaunchKernelGGL(gemmA_k<2>, grid, dim3(256), 0, stream, A, W, bias, R, C, M, N, K);
    }
  };
  auto ln = [&](const float* xi, const in_t* g, const in_t* b, float* o, int rows) {
    hipLaunchKernelGGL(ln_k, dim3((rows+3)/4), dim3(256), 0, stream, xi, g, b, o, rows);
  };

  // ---- 1. patch embedding ----
  {
    int total = BT_*196*768;
    hipLaunchKernelGGL(patchify_k, dim3((total+255)/256), dim3(256), 0, stream, x_in, FF);
    gemm(0, FF, patch_w, patch_b, nullptr, Y, BT_*196, DMODEL, 768);
    int tot2 = BT_*NTOK*DMODEL;
    hipLaunchKernelGGL(assemble_k, dim3((tot2+255)/256), dim3(256), 0, stream, Y, space_tk, pos_emb, X);
  }

  const float sc64 = 0.125f;
  const float sc32 = 0.17677669529663687f;

  // ---- 2. spatial transformer (2 layers, heads=6, dh=64) ----
  for (int i = 0; i < 2; ++i) {
    ln(X, s_ln1_g + (size_t)i*192, s_ln1_b + (size_t)i*192, H, ROWS_);
    gemm(0, H, s_qkv_w + (size_t)i*192*1152, nullptr, nullptr, QKV, ROWS_, 1152, 192);
    hipLaunchKernelGGL((attn2_k<64,8>), dim3(BT_*6), dim3(512), 0, stream, QKV, Y, (float*)nullptr, NTOK, 6, sc64);
    gemm(2, Y, s_out_w + (size_t)i*384*192, s_out_b + (size_t)i*192, X, X, ROWS_, 192, 384);
    ln(X, s_ln2_g + (size_t)i*192, s_ln2_b + (size_t)i*192, H, ROWS_);
    gemm(1, H, s_fc1_w + (size_t)i*192*768, s_fc1_b + (size_t)i*768, nullptr, FF, ROWS_, 768, 192);
    gemm(2, FF, s_fc2_w + (size_t)i*768*192, s_fc2_b + (size_t)i*192, X, X, ROWS_, 192, 768);
  }
  ln(X, s_nrm_g, s_nrm_b, X, ROWS_);

  // ---- 3. ATS blocks (12 layers, heads=6, dh=32) ----
  float* xa = X; float* xb = X2;
  for (int i = 0; i < 12; ++i) {
    ln(xa, a_ln1_g + (size_t)i*192, a_ln1_b + (size_t)i*192, H, ROWS_);
    gemm(0, H, a_qkv_w + (size_t)i*192*576, a_qkv_b + (size_t)i*576, nullptr, QKV, ROWS_, 576, 192);
    hipLaunchKernelGGL((attn2_k<32,4>), dim3(BT_*6), dim3(256), 0, stream, QKV, Y, A0, NTOK, 6, sc32);
    gemm(0, Y, a_prj_w + (size_t)i*192*192, a_prj_b + (size_t)i*192, nullptr, H, ROWS_, 192, 192);
    hipLaunchKernelGGL(score_k, dim3(BT_), dim3(256), 0, stream, A0, QKV, SB);
    hipLaunchKernelGGL(sample_k, dim3(BT_), dim3(256), 0, stream, SB, IDX);
    {
      int tot = BT_*NTOK*DMODEL;
      hipLaunchKernelGGL(gather_k, dim3((tot+255)/256), dim3(256), 0, stream, xa, H, IDX, xb);
    }
    ln(xb, a_ln2_g + (size_t)i*192, a_ln2_b + (size_t)i*192, H, ROWS_);
    gemm(1, H, a_fc1_w + (size_t)i*192*768, a_fc1_b + (size_t)i*768, nullptr, FF, ROWS_, 768, 192);
    gemm(2, FF, a_fc2_w + (size_t)i*768*192, a_fc2_b + (size_t)i*192, xb, xb, ROWS_, 192, 768);
    float* tmp = xa; xa = xb; xb = tmp;
  }

  // ---- 4. temporal transformer (3 layers on [16,6,192]) ----
  {
    int tot = 16*6*DMODEL;
    hipLaunchKernelGGL(build_xc_k, dim3((tot+255)/256), dim3(256), 0, stream, xa, temp_tk, XC);
  }
  const int MT = 16*6;
  for (int i = 0; i < 3; ++i) {
    ln(XC, t_ln1_g + (size_t)i*192, t_ln1_b + (size_t)i*192, H, MT);
    gemm(0, H, t_qkv_w + (size_t)i*192*1152, nullptr, nullptr, QKV, MT, 1152, 192);
    hipLaunchKernelGGL((attn2_k<64,8>), dim3(16*6), dim3(512), 0, stream, QKV, Y, (float*)nullptr, 6, 6, sc64);
    gemm(2, Y, t_out_w + (size_t)i*384*192, t_out_b + (size_t)i*192, XC, XC, MT, 192, 384);
    ln(XC, t_ln2_g + (size_t)i*192, t_ln2_b + (size_t)i*192, H, MT);
    gemm(1, H, t_fc1_w + (size_t)i*192*768, t_fc1_b + (size_t)i*768, nullptr, FF, MT, 768, 192);
    gemm(2, FF, t_fc2_w + (size_t)i*768*192, t_fc2_b + (size_t)i*192, XC, XC, MT, 192, 768);
  }
  ln(XC, t_nrm_g, t_nrm_b, XC, MT);

  // ---- 5. maxpool + final LN + head ----
  hipLaunchKernelGGL(head_k, dim3(16), dim3(256), 0, stream, XC, final_g, final_b,
                     h1_w, h1_b, h2_w, h2_b, (out_t*)d_out);
}

// Round 8
// 6636.352 us; speedup vs baseline: 1.0883x; 1.0883x over previous
//
#include <hip/hip_runtime.h>
#include <hip/hip_bf16.h>
#include <math.h>

typedef float in_t;
typedef float out_t;

__device__ __forceinline__ float ldi(const in_t* p, size_t i) { return (float)p[i]; }

#define DMODEL 192
#define NTOK   197
#define BT_    80
#define ROWS_  (BT_*NTOK)   // 15760

__device__ __forceinline__ float gelu_f(float v) {
  return 0.5f*v*(1.f + tanhf(0.7978845608028654f*(v + 0.044715f*v*v*v)));
}

// ================= GEMM A (round-2 measured best): 64x64, 4x4/thread ======
// Both operands staged in LDS. EPI: 0=bias, 1=bias+gelu, 2=bias+residual(R)
template<int EPI>
__global__ __launch_bounds__(256)
void gemmA_k(const float* __restrict__ A, const in_t* __restrict__ W,
             const in_t* __restrict__ bias, const float* __restrict__ R,
             float* __restrict__ C, int M, int N, int K)
{
  constexpr int BM=64, BN=64, BK=16;
  __shared__ float As[BK][BM+4];
  __shared__ float Ws[BK][BN+4];
  const int t = threadIdx.x;
  const int bm0 = blockIdx.y*BM, bn0 = blockIdx.x*BN;
  const int tm = (t>>4)*4;
  const int tn = (t&15)*4;
  const int la_m = t>>2;
  const int la_k = (t&3)*4;
  const int lw_k = t>>4;
  const int lw_n = (t&15)*4;
  float acc[4][4] = {};
  for (int k0 = 0; k0 < K; k0 += BK) {
    int gm = bm0 + la_m;
    float4 av = make_float4(0.f,0.f,0.f,0.f);
    if (gm < M) av = *(const float4*)(A + (size_t)gm*K + (size_t)(k0 + la_k));
    As[la_k+0][la_m] = av.x; As[la_k+1][la_m] = av.y;
    As[la_k+2][la_m] = av.z; As[la_k+3][la_m] = av.w;
    const in_t* wp = W + (size_t)(k0+lw_k)*N + (size_t)(bn0+lw_n);
    Ws[lw_k][lw_n+0] = ldi(wp,0); Ws[lw_k][lw_n+1] = ldi(wp,1);
    Ws[lw_k][lw_n+2] = ldi(wp,2); Ws[lw_k][lw_n+3] = ldi(wp,3);
    __syncthreads();
    #pragma unroll
    for (int kk=0; kk<BK; ++kk) {
      float4 a4 = *(const float4*)&As[kk][tm];
      float4 b4 = *(const float4*)&Ws[kk][tn];
      float ar[4] = {a4.x,a4.y,a4.z,a4.w};
      float br[4] = {b4.x,b4.y,b4.z,b4.w};
      #pragma unroll
      for (int ii=0; ii<4; ++ii)
        #pragma unroll
        for (int jj=0; jj<4; ++jj)
          acc[ii][jj] = fmaf(ar[ii], br[jj], acc[ii][jj]);
    }
    __syncthreads();
  }
  #pragma unroll
  for (int ii=0; ii<4; ++ii) {
    int gm = bm0 + tm + ii;
    if (gm >= M) continue;
    int gn = bn0 + tn;
    float v0=acc[ii][0], v1=acc[ii][1], v2=acc[ii][2], v3=acc[ii][3];
    if (bias) { v0+=ldi(bias,gn); v1+=ldi(bias,gn+1); v2+=ldi(bias,gn+2); v3+=ldi(bias,gn+3); }
    if (EPI==1) { v0=gelu_f(v0); v1=gelu_f(v1); v2=gelu_f(v2); v3=gelu_f(v3); }
    if (EPI==2) {
      const float4 r4 = *(const float4*)(R + (size_t)gm*N + gn);
      v0+=r4.x; v1+=r4.y; v2+=r4.z; v3+=r4.w;
    }
    *(float4*)(C + (size_t)gm*N + gn) = make_float4(v0,v1,v2,v3);
  }
}

// ================= LayerNorm over width 192 =================
__global__ __launch_bounds__(256)
void ln_k(const float* __restrict__ x, const in_t* __restrict__ g, const in_t* __restrict__ b,
          float* __restrict__ o, int rows)
{
  int t = threadIdx.x, wave = t>>6, lane = t&63;
  int r = blockIdx.x*4 + wave;
  if (r >= rows) return;
  const float* xr = x + (size_t)r*DMODEL;
  float e0 = xr[lane], e1 = xr[lane+64], e2 = xr[lane+128];
  float s = e0+e1+e2;
  #pragma unroll
  for (int off=32; off; off>>=1) s += __shfl_xor(s, off);
  float mean = s / 192.f;
  float d0=e0-mean, d1=e1-mean, d2=e2-mean;
  float v = d0*d0+d1*d1+d2*d2;
  #pragma unroll
  for (int off=32; off; off>>=1) v += __shfl_xor(v, off);
  float rs = 1.f / sqrtf(v/192.f + 1e-6f);
  float* orow = o + (size_t)r*DMODEL;
  orow[lane]     = d0*rs*ldi(g,lane)     + ldi(b,lane);
  orow[lane+64]  = d1*rs*ldi(g,lane+64)  + ldi(b,lane+64);
  orow[lane+128] = d2*rs*ldi(g,lane+128) + ldi(b,lane+128);
}

// ================= Fused attention v2r: attn2 + PV retile =================
// Identical to round-2 attn2 except the PV phase: lanes are re-mapped to
// (part, q-group, d-quad). Each b128 P-broadcast now feeds 16 FMAs (was 4)
// -> PV LDS instruction count /4. V reads float4 (coalesced in-group,
// L1-dedup across groups). Everything else byte-identical to attn2.
template<int DH, int W>
__global__ __launch_bounds__(W*64)
void attn2r_k(const float* __restrict__ qkv, float* __restrict__ out,
              float* __restrict__ attn0, int Nseq, int heads, float scale)
{
  constexpr int QT = 8;
  constexpr int KTS = 204;
  constexpr int NPART = (DH == 64) ? 1 : 2;   // jc interleave for DH=32
  constexpr int DQ   = DH/4;                  // d-quad lanes: 16 / 8
  constexpr int QG   = 4;                     // q-groups
  constexpr int QPG  = 2;                     // q per group
  __shared__ float Kt[DH * KTS];
  __shared__ float Qt[W][DH][12];
  __shared__ float Ps[W][QT][200];

  const int bh = blockIdx.x;
  const int b = bh / heads, h = bh % heads;
  const int stride = 3 * heads * DH;
  const float* __restrict__ base = qkv + (size_t)b * Nseq * stride;
  const int qo = h * DH, ko = heads * DH + h * DH, vo = 2 * heads * DH + h * DH;
  const int t = threadIdx.x, w = t >> 6, lane = t & 63;

  for (int idx = t; idx < Nseq * DH; idx += W * 64) {
    int j = idx / DH, d0 = idx - j * DH;
    Kt[d0 * KTS + j] = base[(size_t)j * stride + ko + d0];
  }
  __syncthreads();

  const int d = lane & (DH - 1);
  const int nchunks = (Nseq + QT - 1) / QT;
  const int jcmax = (Nseq + 3) >> 2;
  const float NEG = -3.0e38f;
  const float4* Kt4 = (const float4*)Kt;

  // PV lane mapping
  const int part = (NPART == 2) ? (lane >> 5) : 0;
  const int qg   = (DH == 64) ? (lane >> 4) : ((lane >> 3) & 3);
  const int dq   = lane & (DQ - 1);
  const int dv   = 4 * dq;

  for (int ic = w; ic < nchunks; ic += W) {
    const int i0 = ic * QT;
    // stage this wave's 8 q rows (same as attn2; for DH=32 lanes 32-63 dup)
    if ((DH == 64) || (lane >> 5) == 0) {
      #pragma unroll
      for (int q = 0; q < QT; ++q) {
        int i = i0 + q;
        Qt[w][d][q] = (i < Nseq) ? base[(size_t)i * stride + qo + d] : 0.f;
      }
    }
    // ---- QK^T: lane l covers j = 4l..4l+3 (unchanged) ----
    float s[QT][4];
    #pragma unroll
    for (int q = 0; q < QT; ++q)
      #pragma unroll
      for (int u = 0; u < 4; ++u) s[q][u] = 0.f;
    #pragma unroll 4
    for (int dd = 0; dd < DH; ++dd) {
      float4 kv = (lane < 51) ? Kt4[dd * (KTS/4) + lane] : make_float4(0.f,0.f,0.f,0.f);
      float4 qA = *(const float4*)&Qt[w][dd][0];
      float4 qB = *(const float4*)&Qt[w][dd][4];
      float qv[8] = {qA.x, qA.y, qA.z, qA.w, qB.x, qB.y, qB.z, qB.w};
      float kr[4] = {kv.x, kv.y, kv.z, kv.w};
      #pragma unroll
      for (int q = 0; q < QT; ++q)
        #pragma unroll
        for (int u = 0; u < 4; ++u)
          s[q][u] = fmaf(qv[q], kr[u], s[q][u]);
    }
    // ---- softmax per row (unchanged) ----
    float inv[QT];
    #pragma unroll
    for (int q = 0; q < QT; ++q) {
      float mx = NEG;
      #pragma unroll
      for (int u = 0; u < 4; ++u) {
        int j = 4*lane + u;
        s[q][u] = (j < Nseq) ? s[q][u]*scale : NEG;
        mx = fmaxf(mx, s[q][u]);
      }
      #pragma unroll
      for (int off = 32; off; off >>= 1) mx = fmaxf(mx, __shfl_xor(mx, off));
      float sum = 0.f;
      #pragma unroll
      for (int u = 0; u < 4; ++u) {
        float p = (4*lane + u < Nseq) ? expf(s[q][u] - mx) : 0.f;
        s[q][u] = p; sum += p;
      }
      #pragma unroll
      for (int off = 32; off; off >>= 1) sum += __shfl_xor(sum, off);
      inv[q] = 1.f / sum;
      if (lane < 50)
        *(float4*)&Ps[w][q][4*lane] = make_float4(s[q][0], s[q][1], s[q][2], s[q][3]);
    }
    if (attn0 != nullptr && i0 == 0) {
      #pragma unroll
      for (int u = 0; u < 4; ++u) {
        int j = 4*lane + u;
        if (j < Nseq) attn0[(size_t)bh*Nseq + j] = s[0][u]*inv[0];
      }
    }
    // ---- PV retiled: lane = (part, qg, dq); P b128 feeds 16 FMA ----
    float o[QPG][4];
    #pragma unroll
    for (int qi = 0; qi < QPG; ++qi) { o[qi][0]=0.f; o[qi][1]=0.f; o[qi][2]=0.f; o[qi][3]=0.f; }
    const float* __restrict__ Vg = base + vo;
    for (int jc = part; jc < jcmax; jc += NPART) {
      const int jb = 4*jc;
      float4 V0 = make_float4(0.f,0.f,0.f,0.f), V1=V0, V2=V0, V3=V0;
      if (jb+0 < Nseq) V0 = *(const float4*)&Vg[(size_t)(jb+0)*stride + dv];
      if (jb+1 < Nseq) V1 = *(const float4*)&Vg[(size_t)(jb+1)*stride + dv];
      if (jb+2 < Nseq) V2 = *(const float4*)&Vg[(size_t)(jb+2)*stride + dv];
      if (jb+3 < Nseq) V3 = *(const float4*)&Vg[(size_t)(jb+3)*stride + dv];
      #pragma unroll
      for (int qi = 0; qi < QPG; ++qi) {
        float4 p4 = *(const float4*)&Ps[w][qg*QPG+qi][jb];
        o[qi][0] = fmaf(p4.w,V3.x, fmaf(p4.z,V2.x, fmaf(p4.y,V1.x, fmaf(p4.x,V0.x, o[qi][0]))));
        o[qi][1] = fmaf(p4.w,V3.y, fmaf(p4.z,V2.y, fmaf(p4.y,V1.y, fmaf(p4.x,V0.y, o[qi][1]))));
        o[qi][2] = fmaf(p4.w,V3.z, fmaf(p4.z,V2.z, fmaf(p4.y,V1.z, fmaf(p4.x,V0.z, o[qi][2]))));
        o[qi][3] = fmaf(p4.w,V3.w, fmaf(p4.z,V2.w, fmaf(p4.y,V1.w, fmaf(p4.x,V0.w, o[qi][3]))));
      }
    }
    if (NPART == 2) {
      #pragma unroll
      for (int qi = 0; qi < QPG; ++qi) {
        o[qi][0] += __shfl_xor(o[qi][0], 32);
        o[qi][1] += __shfl_xor(o[qi][1], 32);
        o[qi][2] += __shfl_xor(o[qi][2], 32);
        o[qi][3] += __shfl_xor(o[qi][3], 32);
      }
    }
    if (part == 0) {
      #pragma unroll
      for (int qi = 0; qi < QPG; ++qi) {
        // compile-time-index select of inv (wave-uniform values, cndmask chain)
        float iv = inv[qi];
        if (qg == 1) iv = inv[QPG + qi];
        if (qg == 2) iv = inv[2*QPG + qi];
        if (qg == 3) iv = inv[3*QPG + qi];
        int i = i0 + qg*QPG + qi;
        if (i < Nseq) {
          float4 r = make_float4(o[qi][0]*iv, o[qi][1]*iv, o[qi][2]*iv, o[qi][3]*iv);
          *(float4*)&out[((size_t)b*Nseq + i)*(size_t)(heads*DH) + h*DH + dv] = r;
        }
      }
    }
  }
}

// ================= patch extraction =================
__global__ void patchify_k(const in_t* __restrict__ x, float* __restrict__ A)
{
  int idx = blockIdx.x*256 + threadIdx.x;
  const int total = BT_*196*768;
  if (idx >= total) return;
  int kc = idx % 768;
  int m  = idx / 768;
  int p  = m % 196;
  int bt = m / 196;
  int c  = kc >> 8;
  int py = (kc >> 4) & 15;
  int px = kc & 15;
  int ph = p / 14, pw = p % 14;
  size_t src = (((size_t)bt*3 + c)*224 + (ph*16+py))*224 + (pw*16+px);
  A[idx] = ldi(x, src);
}

// ================= assemble tokens =================
__global__ void assemble_k(const float* __restrict__ pt, const in_t* __restrict__ st,
                           const in_t* __restrict__ pe, float* __restrict__ X)
{
  int i = blockIdx.x*256 + threadIdx.x;
  const int total = BT_*NTOK*DMODEL;
  if (i >= total) return;
  int d  = i % DMODEL;
  int n  = (i / DMODEL) % NTOK;
  int bt = i / (DMODEL*NTOK);
  int tt = bt % 5;
  float base = (n == 0) ? ldi(st, d)
                        : pt[((size_t)bt*196 + (n-1))*DMODEL + d];
  X[i] = base + ldi(pe, ((size_t)tt*NTOK + n)*DMODEL + d);
}

// ================= ATS significance score =================
__global__ void score_k(const float* __restrict__ attn0, const float* __restrict__ qkv,
                        float* __restrict__ S)
{
  int b = blockIdx.x;
  int jj = threadIdx.x;
  if (jj >= 196) return;
  int j = jj + 1;
  float acc = 0.f;
  #pragma unroll
  for (int h = 0; h < 6; ++h) {
    float a0 = attn0[((size_t)b*6 + h)*NTOK + j];
    const float* v = qkv + ((size_t)b*NTOK + j)*576 + 384 + h*32;
    float ss = 0.f;
    #pragma unroll
    for (int d = 0; d < 32; ++d) ss += v[d]*v[d];
    acc += a0 * sqrtf(ss);
  }
  S[(size_t)b*196 + jj] = acc / 6.0f;
}

// ================= ATS sampling =================
__global__ void sample_k(const float* __restrict__ S, int* __restrict__ idxout)
{
  __shared__ float cdf[196];
  int b = blockIdx.x, t = threadIdx.x;
  if (t == 0) {
    float tot = 0.f;
    for (int k = 0; k < 196; ++k) tot += S[(size_t)b*196 + k];
    float denom = tot + 1e-8f;
    float run = 0.f;
    for (int k = 0; k < 196; ++k) { run += S[(size_t)b*196 + k] / denom; cdf[k] = run; }
    idxout[(size_t)b*NTOK] = 0;
  }
  __syncthreads();
  if (t < 196) {
    float u = ((float)t + 0.5f) / 196.0f;
    int cnt = 0;
    for (int k = 0; k < 196; ++k) cnt += (cdf[k] < u) ? 1 : 0;
    int c = cnt > 195 ? 195 : cnt;
    idxout[(size_t)b*NTOK + 1 + t] = c + 1;
  }
}

// ================= gather =================
__global__ void gather_k(const float* __restrict__ X, const float* __restrict__ P,
                         const int* __restrict__ idx, float* __restrict__ Xo)
{
  int i = blockIdx.x*256 + threadIdx.x;
  const int total = BT_*NTOK*DMODEL;
  if (i >= total) return;
  int d  = i % DMODEL;
  int n  = (i / DMODEL) % NTOK;
  int bt = i / (DMODEL*NTOK);
  int src = idx[(size_t)bt*NTOK + n];
  size_t sr = ((size_t)bt*NTOK + src)*DMODEL + d;
  Xo[i] = X[sr] + P[sr];
}

// ================= build temporal sequence =================
__global__ void build_xc_k(const float* __restrict__ X, const in_t* __restrict__ tt,
                           float* __restrict__ xc)
{
  int i = blockIdx.x*256 + threadIdx.x;
  const int total = 16*6*DMODEL;
  if (i >= total) return;
  int d = i % DMODEL;
  int n = (i / DMODEL) % 6;
  int b = i / (DMODEL*6);
  xc[i] = (n == 0) ? ldi(tt, d)
                   : X[(((size_t)b*5 + (n-1))*NTOK + 0)*DMODEL + d];
}

// ================= maxpool + final LN + MLP head =================
__global__ __launch_bounds__(256)
void head_k(const float* __restrict__ xc, const in_t* __restrict__ fg, const in_t* __restrict__ fb,
            const in_t* __restrict__ w1, const in_t* __restrict__ b1,
            const in_t* __restrict__ w2, const in_t* __restrict__ b2,
            out_t* __restrict__ outp)
{
  __shared__ float fn[DMODEL];
  __shared__ float hid[64];
  __shared__ float mv[2];
  int b = blockIdx.x, t = threadIdx.x;
  if (t < DMODEL) {
    float m = xc[((size_t)b*6 + 0)*DMODEL + t];
    #pragma unroll
    for (int n = 1; n < 6; ++n) m = fmaxf(m, xc[((size_t)b*6 + n)*DMODEL + t]);
    fn[t] = m;
  }
  __syncthreads();
  if (t == 0) {
    float s = 0.f;
    for (int d = 0; d < DMODEL; ++d) s += fn[d];
    float mean = s / 192.f;
    float v = 0.f;
    for (int d = 0; d < DMODEL; ++d) { float dd = fn[d]-mean; v += dd*dd; }
    mv[0] = mean; mv[1] = 1.f / sqrtf(v/192.f + 1e-6f);
  }
  __syncthreads();
  if (t < DMODEL) fn[t] = (fn[t]-mv[0])*mv[1]*ldi(fg,t) + ldi(fb,t);
  __syncthreads();
  if (t < 64) {
    float a = ldi(b1, t);
    for (int d = 0; d < DMODEL; ++d) a += fn[d]*ldi(w1, (size_t)d*64 + t);
    hid[t] = fmaxf(a, 0.f);
  }
  __syncthreads();
  if (t < 2) {
    float a = ldi(b2, t);
    for (int j = 0; j < 64; ++j) a += hid[j]*ldi(w2, (size_t)j*2 + t);
    outp[(size_t)b*2 + t] = (out_t)a;
  }
}

// =========================================================================
extern "C" void kernel_launch(void* const* d_in, const int* in_sizes, int n_in,
                              void* d_out, int out_size, void* d_ws, size_t ws_size,
                              hipStream_t stream)
{
  if (n_in < 50) return;
  const in_t* x_in     = (const in_t*)d_in[0];
  const in_t* patch_w  = (const in_t*)d_in[1];
  const in_t* patch_b  = (const in_t*)d_in[2];
  const in_t* pos_emb  = (const in_t*)d_in[3];
  const in_t* space_tk = (const in_t*)d_in[4];
  const in_t* temp_tk  = (const in_t*)d_in[5];
  const in_t* s_ln1_g = (const in_t*)d_in[6];  const in_t* s_ln1_b = (const in_t*)d_in[7];
  const in_t* s_qkv_w = (const in_t*)d_in[8];  const in_t* s_out_w = (const in_t*)d_in[9];
  const in_t* s_out_b = (const in_t*)d_in[10]; const in_t* s_ln2_g = (const in_t*)d_in[11];
  const in_t* s_ln2_b = (const in_t*)d_in[12]; const in_t* s_fc1_w = (const in_t*)d_in[13];
  const in_t* s_fc1_b = (const in_t*)d_in[14]; const in_t* s_fc2_w = (const in_t*)d_in[15];
  const in_t* s_fc2_b = (const in_t*)d_in[16]; const in_t* s_nrm_g = (const in_t*)d_in[17];
  const in_t* s_nrm_b = (const in_t*)d_in[18];
  const in_t* t_ln1_g = (const in_t*)d_in[19]; const in_t* t_ln1_b = (const in_t*)d_in[20];
  const in_t* t_qkv_w = (const in_t*)d_in[21]; const in_t* t_out_w = (const in_t*)d_in[22];
  const in_t* t_out_b = (const in_t*)d_in[23]; const in_t* t_ln2_g = (const in_t*)d_in[24];
  const in_t* t_ln2_b = (const in_t*)d_in[25]; const in_t* t_fc1_w = (const in_t*)d_in[26];
  const in_t* t_fc1_b = (const in_t*)d_in[27]; const in_t* t_fc2_w = (const in_t*)d_in[28];
  const in_t* t_fc2_b = (const in_t*)d_in[29]; const in_t* t_nrm_g = (const in_t*)d_in[30];
  const in_t* t_nrm_b = (const in_t*)d_in[31];
  const in_t* a_ln1_g = (const in_t*)d_in[32]; const in_t* a_ln1_b = (const in_t*)d_in[33];
  const in_t* a_qkv_w = (const in_t*)d_in[34]; const in_t* a_qkv_b = (const in_t*)d_in[35];
  const in_t* a_prj_w = (const in_t*)d_in[36]; const in_t* a_prj_b = (const in_t*)d_in[37];
  const in_t* a_ln2_g = (const in_t*)d_in[38]; const in_t* a_ln2_b = (const in_t*)d_in[39];
  const in_t* a_fc1_w = (const in_t*)d_in[40]; const in_t* a_fc1_b = (const in_t*)d_in[41];
  const in_t* a_fc2_w = (const in_t*)d_in[42]; const in_t* a_fc2_b = (const in_t*)d_in[43];
  const in_t* final_g = (const in_t*)d_in[44]; const in_t* final_b = (const in_t*)d_in[45];
  const in_t* h1_w = (const in_t*)d_in[46];    const in_t* h1_b = (const in_t*)d_in[47];
  const in_t* h2_w = (const in_t*)d_in[48];    const in_t* h2_b = (const in_t*)d_in[49];

  float* ws = (float*)d_ws;
  size_t off = 0;
  auto alloc = [&](size_t nf) { size_t r = off; off += (nf + 63) & ~((size_t)63); return r; };
  size_t oX   = alloc((size_t)ROWS_*DMODEL);
  size_t oX2  = alloc((size_t)ROWS_*DMODEL);
  size_t oH   = alloc((size_t)ROWS_*DMODEL);
  size_t oQKV = alloc((size_t)ROWS_*1152);
  size_t oY   = alloc((size_t)ROWS_*384);
  size_t oFF  = alloc((size_t)ROWS_*768);
  size_t oA0  = alloc((size_t)480*NTOK);
  size_t oSB  = alloc((size_t)BT_*196);
  size_t oXC  = alloc((size_t)16*6*DMODEL);
  size_t oIDX = alloc((size_t)BT_*NTOK);
  if (ws_size < off*sizeof(float)) return;

  float* X   = ws + oX;
  float* X2  = ws + oX2;
  float* H   = ws + oH;
  float* QKV = ws + oQKV;
  float* Y   = ws + oY;
  float* FF  = ws + oFF;
  float* A0  = ws + oA0;
  float* SB  = ws + oSB;
  float* XC  = ws + oXC;
  int*   IDX = (int*)(ws + oIDX);

  auto gemm = [&](int epi, const float* A, const in_t* W, const in_t* bias,
                  const float* R, float* C, int M, int N, int K) {
    dim3 grid(N/64, (M+63)/64);
    if (epi == 0)      hipLaunchKernelGGL(gemmA_k<0>, grid, dim3(256), 0, stream, A, W, bias, R, C, M, N, K);
    else if (epi == 1) hipLaunchKernelGGL(gemmA_k<1>, grid, dim3(256), 0, stream, A, W, bias, R, C, M, N, K);
    else               hipLaunchKernelGGL(gemmA_k<2>, grid, dim3(256), 0, stream, A, W, bias, R, C, M, N, K);
  };
  auto ln = [&](const float* xi, const in_t* g, const in_t* b, float* o, int rows) {
    hipLaunchKernelGGL(ln_k, dim3((rows+3)/4), dim3(256), 0, stream, xi, g, b, o, rows);
  };

  // ---- 1. patch embedding ----
  {
    int total = BT_*196*768;
    hipLaunchKernelGGL(patchify_k, dim3((total+255)/256), dim3(256), 0, stream, x_in, FF);
    gemm(0, FF, patch_w, patch_b, nullptr, Y, BT_*196, DMODEL, 768);
    int tot2 = BT_*NTOK*DMODEL;
    hipLaunchKernelGGL(assemble_k, dim3((tot2+255)/256), dim3(256), 0, stream, Y, space_tk, pos_emb, X);
  }

  const float sc64 = 0.125f;
  const float sc32 = 0.17677669529663687f;

  // ---- 2. spatial transformer (2 layers, heads=6, dh=64) ----
  for (int i = 0; i < 2; ++i) {
    ln(X, s_ln1_g + (size_t)i*192, s_ln1_b + (size_t)i*192, H, ROWS_);
    gemm(0, H, s_qkv_w + (size_t)i*192*1152, nullptr, nullptr, QKV, ROWS_, 1152, 192);
    hipLaunchKernelGGL((attn2r_k<64,8>), dim3(BT_*6), dim3(512), 0, stream, QKV, Y, (float*)nullptr, NTOK, 6, sc64);
    gemm(2, Y, s_out_w + (size_t)i*384*192, s_out_b + (size_t)i*192, X, X, ROWS_, 192, 384);
    ln(X, s_ln2_g + (size_t)i*192, s_ln2_b + (size_t)i*192, H, ROWS_);
    gemm(1, H, s_fc1_w + (size_t)i*192*768, s_fc1_b + (size_t)i*768, nullptr, FF, ROWS_, 768, 192);
    gemm(2, FF, s_fc2_w + (size_t)i*768*192, s_fc2_b + (size_t)i*192, X, X, ROWS_, 192, 768);
  }
  ln(X, s_nrm_g, s_nrm_b, X, ROWS_);

  // ---- 3. ATS blocks (12 layers, heads=6, dh=32) ----
  float* xa = X; float* xb = X2;
  for (int i = 0; i < 12; ++i) {
    ln(xa, a_ln1_g + (size_t)i*192, a_ln1_b + (size_t)i*192, H, ROWS_);
    gemm(0, H, a_qkv_w + (size_t)i*192*576, a_qkv_b + (size_t)i*576, nullptr, QKV, ROWS_, 576, 192);
    hipLaunchKernelGGL((attn2r_k<32,4>), dim3(BT_*6), dim3(256), 0, stream, QKV, Y, A0, NTOK, 6, sc32);
    gemm(0, Y, a_prj_w + (size_t)i*192*192, a_prj_b + (size_t)i*192, nullptr, H, ROWS_, 192, 192);
    hipLaunchKernelGGL(score_k, dim3(BT_), dim3(256), 0, stream, A0, QKV, SB);
    hipLaunchKernelGGL(sample_k, dim3(BT_), dim3(256), 0, stream, SB, IDX);
    {
      int tot = BT_*NTOK*DMODEL;
      hipLaunchKernelGGL(gather_k, dim3((tot+255)/256), dim3(256), 0, stream, xa, H, IDX, xb);
    }
    ln(xb, a_ln2_g + (size_t)i*192, a_ln2_b + (size_t)i*192, H, ROWS_);
    gemm(1, H, a_fc1_w + (size_t)i*192*768, a_fc1_b + (size_t)i*768, nullptr, FF, ROWS_, 768, 192);
    gemm(2, FF, a_fc2_w + (size_t)i*768*192, a_fc2_b + (size_t)i*192, xb, xb, ROWS_, 192, 768);
    float* tmp = xa; xa = xb; xb = tmp;
  }

  // ---- 4. temporal transformer (3 layers on [16,6,192]) ----
  {
    int tot = 16*6*DMODEL;
    hipLaunchKernelGGL(build_xc_k, dim3((tot+255)/256), dim3(256), 0, stream, xa, temp_tk, XC);
  }
  const int MT = 16*6;
  for (int i = 0; i < 3; ++i) {
    ln(XC, t_ln1_g + (size_t)i*192, t_ln1_b + (size_t)i*192, H, MT);
    gemm(0, H, t_qkv_w + (size_t)i*192*1152, nullptr, nullptr, QKV, MT, 1152, 192);
    hipLaunchKernelGGL((attn2r_k<64,8>), dim3(16*6), dim3(512), 0, stream, QKV, Y, (float*)nullptr, 6, 6, sc64);
    gemm(2, Y, t_out_w + (size_t)i*384*192, t_out_b + (size_t)i*192, XC, XC, MT, 192, 384);
    ln(XC, t_ln2_g + (size_t)i*192, t_ln2_b + (size_t)i*192, H, MT);
    gemm(1, H, t_fc1_w + (size_t)i*192*768, t_fc1_b + (size_t)i*768, nullptr, FF, MT, 768, 192);
    gemm(2, FF, t_fc2_w + (size_t)i*768*192, t_fc2_b + (size_t)i*192, XC, XC, MT, 192, 768);
  }
  ln(XC, t_nrm_g, t_nrm_b, XC, MT);

  // ---- 5. maxpool + final LN + head ----
  hipLaunchKernelGGL(head_k, dim3(16), dim3(256), 0, stream, XC, final_g, final_b,
                     h1_w, h1_b, h2_w, h2_b, (out_t*)d_out);
}

// Round 9
// 4734.093 us; speedup vs baseline: 1.5256x; 1.4018x over previous
//
#include <hip/hip_runtime.h>
#include <hip/hip_bf16.h>
#include <math.h>

typedef float in_t;
typedef float out_t;

__device__ __forceinline__ float ldi(const in_t* p, size_t i) { return (float)p[i]; }

#define DMODEL 192
#define NTOK   197
#define BT_    80
#define ROWS_  (BT_*NTOK)   // 15760

__device__ __forceinline__ float gelu_f(float v) {
  return 0.5f*v*(1.f + tanhf(0.7978845608028654f*(v + 0.044715f*v*v*v)));
}

// fp32 -> bf16 (RNE)
__device__ __forceinline__ short f2bf(float f) {
  union { float f; unsigned u; } v; v.f = f;
  unsigned r = v.u + 0x7FFFu + ((v.u >> 16) & 1u);
  return (short)(r >> 16);
}

typedef __attribute__((ext_vector_type(8))) short bfrag;   // 8 bf16 = 4 VGPRs
typedef __attribute__((ext_vector_type(4))) float f32x4;

// ============ weight convert+transpose: W[l][K][N] fp32 -> O[l][N][K] bf16 ====
__global__ __launch_bounds__(256)
void wconv_k(const float* __restrict__ W, short* __restrict__ O, int K, int N)
{
  __shared__ float tile[32][33];
  const int l = blockIdx.z;
  const int k0 = blockIdx.y*32, n0 = blockIdx.x*32;
  const float* Wl = W + (size_t)l*K*N;
  short* Ol = O + (size_t)l*K*N;
  const int tx = threadIdx.x & 31, ty = threadIdx.x >> 5;   // 32 x 8
  #pragma unroll
  for (int r = ty; r < 32; r += 8) {
    int k = k0 + r, n = n0 + tx;
    tile[r][tx] = (k < K && n < N) ? Wl[(size_t)k*N + n] : 0.f;
  }
  __syncthreads();
  #pragma unroll
  for (int r = ty; r < 32; r += 8) {
    int n = n0 + r, k = k0 + tx;
    if (n < N && k < K) Ol[(size_t)n*K + k] = f2bf(tile[tx][r]);
  }
}

// ============ MFMA GEMM: C = epi(A[M,K]fp32 @ W) with Wt[N][K] bf16 =========
// 64x64x(BK=32) tile, 4 waves; wave w computes rows w*16..+15 x all 64 cols
// via 4x mfma_f32_16x16x32_bf16, fp32 accum. EPI: 0=bias,1=+gelu,2=+residual.
template<int EPI>
__global__ __launch_bounds__(256)
void gemmM_k(const float* __restrict__ A, const short* __restrict__ Wt,
             const in_t* __restrict__ bias, const float* __restrict__ R,
             float* __restrict__ C, int M, int N, int K)
{
  constexpr int BM=64, BN=64, BK=32, LP=BK+8;   // pitch 40 shorts = 80B
  __shared__ short Asb[BM][LP];
  __shared__ short Bsb[BN][LP];
  const int t = threadIdx.x;
  const int w = t >> 6, lane = t & 63;
  const int bm0 = blockIdx.y*BM, bn0 = blockIdx.x*BN;
  const int sr = t >> 2;          // staging row 0..63
  const int sk = (t & 3) * 8;     // k offset 0,8,16,24
  f32x4 acc[4] = {};

  for (int k0 = 0; k0 < K; k0 += BK) {
    // ---- stage A (fp32 -> bf16) ----
    {
      int gm = bm0 + sr;
      short y[8];
      if (gm < M) {
        const float* ap = A + (size_t)gm*K + k0 + sk;
        float4 v0 = *(const float4*)ap;
        float4 v1 = *(const float4*)(ap + 4);
        y[0]=f2bf(v0.x); y[1]=f2bf(v0.y); y[2]=f2bf(v0.z); y[3]=f2bf(v0.w);
        y[4]=f2bf(v1.x); y[5]=f2bf(v1.y); y[6]=f2bf(v1.z); y[7]=f2bf(v1.w);
      } else {
        #pragma unroll
        for (int i=0;i<8;++i) y[i]=0;
      }
      *(bfrag*)&Asb[sr][sk] = *(bfrag*)y;
      // ---- stage B (bf16 copy from pre-transposed weights) ----
      bfrag bv = *(const bfrag*)(Wt + (size_t)(bn0 + sr)*K + k0 + sk);
      *(bfrag*)&Bsb[sr][sk] = bv;
    }
    __syncthreads();
    // ---- fragments + 4 MFMA ----
    const int fr = lane & 15, kg = (lane >> 4) * 8;
    bfrag af = *(const bfrag*)&Asb[w*16 + fr][kg];
    #pragma unroll
    for (int nt = 0; nt < 4; ++nt) {
      bfrag bf = *(const bfrag*)&Bsb[nt*16 + fr][kg];
      acc[nt] = __builtin_amdgcn_mfma_f32_16x16x32_bf16(af, bf, acc[nt], 0, 0, 0);
    }
    __syncthreads();
  }
  // ---- epilogue: C[w*16 + (lane>>4)*4 + r][nt*16 + (lane&15)] ----
  const int col = lane & 15, rg = (lane >> 4) * 4;
  #pragma unroll
  for (int nt = 0; nt < 4; ++nt) {
    int gn = bn0 + nt*16 + col;
    float bv = bias ? ldi(bias, gn) : 0.f;
    #pragma unroll
    for (int r = 0; r < 4; ++r) {
      int gm = bm0 + w*16 + rg + r;
      if (gm < M) {
        float v = acc[nt][r] + bv;
        if (EPI==1) v = gelu_f(v);
        if (EPI==2) v += R[(size_t)gm*N + gn];
        C[(size_t)gm*N + gn] = v;
      }
    }
  }
}

// ================= LayerNorm over width 192 =================
__global__ __launch_bounds__(256)
void ln_k(const float* __restrict__ x, const in_t* __restrict__ g, const in_t* __restrict__ b,
          float* __restrict__ o, int rows)
{
  int t = threadIdx.x, wave = t>>6, lane = t&63;
  int r = blockIdx.x*4 + wave;
  if (r >= rows) return;
  const float* xr = x + (size_t)r*DMODEL;
  float e0 = xr[lane], e1 = xr[lane+64], e2 = xr[lane+128];
  float s = e0+e1+e2;
  #pragma unroll
  for (int off=32; off; off>>=1) s += __shfl_xor(s, off);
  float mean = s / 192.f;
  float d0=e0-mean, d1=e1-mean, d2=e2-mean;
  float v = d0*d0+d1*d1+d2*d2;
  #pragma unroll
  for (int off=32; off; off>>=1) v += __shfl_xor(v, off);
  float rs = 1.f / sqrtf(v/192.f + 1e-6f);
  float* orow = o + (size_t)r*DMODEL;
  orow[lane]     = d0*rs*ldi(g,lane)     + ldi(b,lane);
  orow[lane+64]  = d1*rs*ldi(g,lane+64)  + ldi(b,lane+64);
  orow[lane+128] = d2*rs*ldi(g,lane+128) + ldi(b,lane+128);
}

// ================= Fused attention v2r (round-8 measured) ==================
template<int DH, int W>
__global__ __launch_bounds__(W*64)
void attn2r_k(const float* __restrict__ qkv, float* __restrict__ out,
              float* __restrict__ attn0, int Nseq, int heads, float scale)
{
  constexpr int QT = 8;
  constexpr int KTS = 204;
  constexpr int NPART = (DH == 64) ? 1 : 2;
  constexpr int DQ   = DH/4;
  constexpr int QPG  = 2;
  __shared__ float Kt[DH * KTS];
  __shared__ float Qt[W][DH][12];
  __shared__ float Ps[W][QT][200];

  const int bh = blockIdx.x;
  const int b = bh / heads, h = bh % heads;
  const int stride = 3 * heads * DH;
  const float* __restrict__ base = qkv + (size_t)b * Nseq * stride;
  const int qo = h * DH, ko = heads * DH + h * DH, vo = 2 * heads * DH + h * DH;
  const int t = threadIdx.x, w = t >> 6, lane = t & 63;

  for (int idx = t; idx < Nseq * DH; idx += W * 64) {
    int j = idx / DH, d0 = idx - j * DH;
    Kt[d0 * KTS + j] = base[(size_t)j * stride + ko + d0];
  }
  __syncthreads();

  const int d = lane & (DH - 1);
  const int nchunks = (Nseq + QT - 1) / QT;
  const int jcmax = (Nseq + 3) >> 2;
  const float NEG = -3.0e38f;
  const float4* Kt4 = (const float4*)Kt;

  const int part = (NPART == 2) ? (lane >> 5) : 0;
  const int qg   = (DH == 64) ? (lane >> 4) : ((lane >> 3) & 3);
  const int dq   = lane & (DQ - 1);
  const int dv   = 4 * dq;

  for (int ic = w; ic < nchunks; ic += W) {
    const int i0 = ic * QT;
    if ((DH == 64) || (lane >> 5) == 0) {
      #pragma unroll
      for (int q = 0; q < QT; ++q) {
        int i = i0 + q;
        Qt[w][d][q] = (i < Nseq) ? base[(size_t)i * stride + qo + d] : 0.f;
      }
    }
    float s[QT][4];
    #pragma unroll
    for (int q = 0; q < QT; ++q)
      #pragma unroll
      for (int u = 0; u < 4; ++u) s[q][u] = 0.f;
    #pragma unroll 4
    for (int dd = 0; dd < DH; ++dd) {
      float4 kv = (lane < 51) ? Kt4[dd * (KTS/4) + lane] : make_float4(0.f,0.f,0.f,0.f);
      float4 qA = *(const float4*)&Qt[w][dd][0];
      float4 qB = *(const float4*)&Qt[w][dd][4];
      float qv[8] = {qA.x, qA.y, qA.z, qA.w, qB.x, qB.y, qB.z, qB.w};
      float kr[4] = {kv.x, kv.y, kv.z, kv.w};
      #pragma unroll
      for (int q = 0; q < QT; ++q)
        #pragma unroll
        for (int u = 0; u < 4; ++u)
          s[q][u] = fmaf(qv[q], kr[u], s[q][u]);
    }
    float inv[QT];
    #pragma unroll
    for (int q = 0; q < QT; ++q) {
      float mx = NEG;
      #pragma unroll
      for (int u = 0; u < 4; ++u) {
        int j = 4*lane + u;
        s[q][u] = (j < Nseq) ? s[q][u]*scale : NEG;
        mx = fmaxf(mx, s[q][u]);
      }
      #pragma unroll
      for (int off = 32; off; off >>= 1) mx = fmaxf(mx, __shfl_xor(mx, off));
      float sum = 0.f;
      #pragma unroll
      for (int u = 0; u < 4; ++u) {
        float p = (4*lane + u < Nseq) ? expf(s[q][u] - mx) : 0.f;
        s[q][u] = p; sum += p;
      }
      #pragma unroll
      for (int off = 32; off; off >>= 1) sum += __shfl_xor(sum, off);
      inv[q] = 1.f / sum;
      if (lane < 50)
        *(float4*)&Ps[w][q][4*lane] = make_float4(s[q][0], s[q][1], s[q][2], s[q][3]);
    }
    if (attn0 != nullptr && i0 == 0) {
      #pragma unroll
      for (int u = 0; u < 4; ++u) {
        int j = 4*lane + u;
        if (j < Nseq) attn0[(size_t)bh*Nseq + j] = s[0][u]*inv[0];
      }
    }
    float o[QPG][4];
    #pragma unroll
    for (int qi = 0; qi < QPG; ++qi) { o[qi][0]=0.f; o[qi][1]=0.f; o[qi][2]=0.f; o[qi][3]=0.f; }
    const float* __restrict__ Vg = base + vo;
    for (int jc = part; jc < jcmax; jc += NPART) {
      const int jb = 4*jc;
      float4 V0 = make_float4(0.f,0.f,0.f,0.f), V1=V0, V2=V0, V3=V0;
      if (jb+0 < Nseq) V0 = *(const float4*)&Vg[(size_t)(jb+0)*stride + dv];
      if (jb+1 < Nseq) V1 = *(const float4*)&Vg[(size_t)(jb+1)*stride + dv];
      if (jb+2 < Nseq) V2 = *(const float4*)&Vg[(size_t)(jb+2)*stride + dv];
      if (jb+3 < Nseq) V3 = *(const float4*)&Vg[(size_t)(jb+3)*stride + dv];
      #pragma unroll
      for (int qi = 0; qi < QPG; ++qi) {
        float4 p4 = *(const float4*)&Ps[w][qg*QPG+qi][jb];
        o[qi][0] = fmaf(p4.w,V3.x, fmaf(p4.z,V2.x, fmaf(p4.y,V1.x, fmaf(p4.x,V0.x, o[qi][0]))));
        o[qi][1] = fmaf(p4.w,V3.y, fmaf(p4.z,V2.y, fmaf(p4.y,V1.y, fmaf(p4.x,V0.y, o[qi][1]))));
        o[qi][2] = fmaf(p4.w,V3.z, fmaf(p4.z,V2.z, fmaf(p4.y,V1.z, fmaf(p4.x,V0.z, o[qi][2]))));
        o[qi][3] = fmaf(p4.w,V3.w, fmaf(p4.z,V2.w, fmaf(p4.y,V1.w, fmaf(p4.x,V0.w, o[qi][3]))));
      }
    }
    if (NPART == 2) {
      #pragma unroll
      for (int qi = 0; qi < QPG; ++qi) {
        o[qi][0] += __shfl_xor(o[qi][0], 32);
        o[qi][1] += __shfl_xor(o[qi][1], 32);
        o[qi][2] += __shfl_xor(o[qi][2], 32);
        o[qi][3] += __shfl_xor(o[qi][3], 32);
      }
    }
    if (part == 0) {
      #pragma unroll
      for (int qi = 0; qi < QPG; ++qi) {
        float iv = inv[qi];
        if (qg == 1) iv = inv[QPG + qi];
        if (qg == 2) iv = inv[2*QPG + qi];
        if (qg == 3) iv = inv[3*QPG + qi];
        int i = i0 + qg*QPG + qi;
        if (i < Nseq) {
          float4 r = make_float4(o[qi][0]*iv, o[qi][1]*iv, o[qi][2]*iv, o[qi][3]*iv);
          *(float4*)&out[((size_t)b*Nseq + i)*(size_t)(heads*DH) + h*DH + dv] = r;
        }
      }
    }
  }
}

// ================= patch extraction =================
__global__ void patchify_k(const in_t* __restrict__ x, float* __restrict__ A)
{
  int idx = blockIdx.x*256 + threadIdx.x;
  const int total = BT_*196*768;
  if (idx >= total) return;
  int kc = idx % 768;
  int m  = idx / 768;
  int p  = m % 196;
  int bt = m / 196;
  int c  = kc >> 8;
  int py = (kc >> 4) & 15;
  int px = kc & 15;
  int ph = p / 14, pw = p % 14;
  size_t src = (((size_t)bt*3 + c)*224 + (ph*16+py))*224 + (pw*16+px);
  A[idx] = ldi(x, src);
}

// ================= assemble tokens =================
__global__ void assemble_k(const float* __restrict__ pt, const in_t* __restrict__ st,
                           const in_t* __restrict__ pe, float* __restrict__ X)
{
  int i = blockIdx.x*256 + threadIdx.x;
  const int total = BT_*NTOK*DMODEL;
  if (i >= total) return;
  int d  = i % DMODEL;
  int n  = (i / DMODEL) % NTOK;
  int bt = i / (DMODEL*NTOK);
  int tt = bt % 5;
  float base = (n == 0) ? ldi(st, d)
                        : pt[((size_t)bt*196 + (n-1))*DMODEL + d];
  X[i] = base + ldi(pe, ((size_t)tt*NTOK + n)*DMODEL + d);
}

// ================= ATS significance score =================
__global__ void score_k(const float* __restrict__ attn0, const float* __restrict__ qkv,
                        float* __restrict__ S)
{
  int b = blockIdx.x;
  int jj = threadIdx.x;
  if (jj >= 196) return;
  int j = jj + 1;
  float acc = 0.f;
  #pragma unroll
  for (int h = 0; h < 6; ++h) {
    float a0 = attn0[((size_t)b*6 + h)*NTOK + j];
    const float* v = qkv + ((size_t)b*NTOK + j)*576 + 384 + h*32;
    float ss = 0.f;
    #pragma unroll
    for (int d = 0; d < 32; ++d) ss += v[d]*v[d];
    acc += a0 * sqrtf(ss);
  }
  S[(size_t)b*196 + jj] = acc / 6.0f;
}

// ================= ATS sampling =================
__global__ void sample_k(const float* __restrict__ S, int* __restrict__ idxout)
{
  __shared__ float cdf[196];
  int b = blockIdx.x, t = threadIdx.x;
  if (t == 0) {
    float tot = 0.f;
    for (int k = 0; k < 196; ++k) tot += S[(size_t)b*196 + k];
    float denom = tot + 1e-8f;
    float run = 0.f;
    for (int k = 0; k < 196; ++k) { run += S[(size_t)b*196 + k] / denom; cdf[k] = run; }
    idxout[(size_t)b*NTOK] = 0;
  }
  __syncthreads();
  if (t < 196) {
    float u = ((float)t + 0.5f) / 196.0f;
    int cnt = 0;
    for (int k = 0; k < 196; ++k) cnt += (cdf[k] < u) ? 1 : 0;
    int c = cnt > 195 ? 195 : cnt;
    idxout[(size_t)b*NTOK + 1 + t] = c + 1;
  }
}

// ================= gather =================
__global__ void gather_k(const float* __restrict__ X, const float* __restrict__ P,
                         const int* __restrict__ idx, float* __restrict__ Xo)
{
  int i = blockIdx.x*256 + threadIdx.x;
  const int total = BT_*NTOK*DMODEL;
  if (i >= total) return;
  int d  = i % DMODEL;
  int n  = (i / DMODEL) % NTOK;
  int bt = i / (DMODEL*NTOK);
  int src = idx[(size_t)bt*NTOK + n];
  size_t sr = ((size_t)bt*NTOK + src)*DMODEL + d;
  Xo[i] = X[sr] + P[sr];
}

// ================= build temporal sequence =================
__global__ void build_xc_k(const float* __restrict__ X, const in_t* __restrict__ tt,
                           float* __restrict__ xc)
{
  int i = blockIdx.x*256 + threadIdx.x;
  const int total = 16*6*DMODEL;
  if (i >= total) return;
  int d = i % DMODEL;
  int n = (i / DMODEL) % 6;
  int b = i / (DMODEL*6);
  xc[i] = (n == 0) ? ldi(tt, d)
                   : X[(((size_t)b*5 + (n-1))*NTOK + 0)*DMODEL + d];
}

// ================= maxpool + final LN + MLP head =================
__global__ __launch_bounds__(256)
void head_k(const float* __restrict__ xc, const in_t* __restrict__ fg, const in_t* __restrict__ fb,
            const in_t* __restrict__ w1, const in_t* __restrict__ b1,
            const in_t* __restrict__ w2, const in_t* __restrict__ b2,
            out_t* __restrict__ outp)
{
  __shared__ float fn[DMODEL];
  __shared__ float hid[64];
  __shared__ float mv[2];
  int b = blockIdx.x, t = threadIdx.x;
  if (t < DMODEL) {
    float m = xc[((size_t)b*6 + 0)*DMODEL + t];
    #pragma unroll
    for (int n = 1; n < 6; ++n) m = fmaxf(m, xc[((size_t)b*6 + n)*DMODEL + t]);
    fn[t] = m;
  }
  __syncthreads();
  if (t == 0) {
    float s = 0.f;
    for (int d = 0; d < DMODEL; ++d) s += fn[d];
    float mean = s / 192.f;
    float v = 0.f;
    for (int d = 0; d < DMODEL; ++d) { float dd = fn[d]-mean; v += dd*dd; }
    mv[0] = mean; mv[1] = 1.f / sqrtf(v/192.f + 1e-6f);
  }
  __syncthreads();
  if (t < DMODEL) fn[t] = (fn[t]-mv[0])*mv[1]*ldi(fg,t) + ldi(fb,t);
  __syncthreads();
  if (t < 64) {
    float a = ldi(b1, t);
    for (int d = 0; d < DMODEL; ++d) a += fn[d]*ldi(w1, (size_t)d*64 + t);
    hid[t] = fmaxf(a, 0.f);
  }
  __syncthreads();
  if (t < 2) {
    float a = ldi(b2, t);
    for (int j = 0; j < 64; ++j) a += hid[j]*ldi(w2, (size_t)j*2 + t);
    outp[(size_t)b*2 + t] = (out_t)a;
  }
}

// =========================================================================
extern "C" void kernel_launch(void* const* d_in, const int* in_sizes, int n_in,
                              void* d_out, int out_size, void* d_ws, size_t ws_size,
                              hipStream_t stream)
{
  if (n_in < 50) return;
  const in_t* x_in     = (const in_t*)d_in[0];
  const in_t* patch_w  = (const in_t*)d_in[1];
  const in_t* patch_b  = (const in_t*)d_in[2];
  const in_t* pos_emb  = (const in_t*)d_in[3];
  const in_t* space_tk = (const in_t*)d_in[4];
  const in_t* temp_tk  = (const in_t*)d_in[5];
  const in_t* s_ln1_g = (const in_t*)d_in[6];  const in_t* s_ln1_b = (const in_t*)d_in[7];
  const in_t* s_qkv_w = (const in_t*)d_in[8];  const in_t* s_out_w = (const in_t*)d_in[9];
  const in_t* s_out_b = (const in_t*)d_in[10]; const in_t* s_ln2_g = (const in_t*)d_in[11];
  const in_t* s_ln2_b = (const in_t*)d_in[12]; const in_t* s_fc1_w = (const in_t*)d_in[13];
  const in_t* s_fc1_b = (const in_t*)d_in[14]; const in_t* s_fc2_w = (const in_t*)d_in[15];
  const in_t* s_fc2_b = (const in_t*)d_in[16]; const in_t* s_nrm_g = (const in_t*)d_in[17];
  const in_t* s_nrm_b = (const in_t*)d_in[18];
  const in_t* t_ln1_g = (const in_t*)d_in[19]; const in_t* t_ln1_b = (const in_t*)d_in[20];
  const in_t* t_qkv_w = (const in_t*)d_in[21]; const in_t* t_out_w = (const in_t*)d_in[22];
  const in_t* t_out_b = (const in_t*)d_in[23]; const in_t* t_ln2_g = (const in_t*)d_in[24];
  const in_t* t_ln2_b = (const in_t*)d_in[25]; const in_t* t_fc1_w = (const in_t*)d_in[26];
  const in_t* t_fc1_b = (const in_t*)d_in[27]; const in_t* t_fc2_w = (const in_t*)d_in[28];
  const in_t* t_fc2_b = (const in_t*)d_in[29]; const in_t* t_nrm_g = (const in_t*)d_in[30];
  const in_t* t_nrm_b = (const in_t*)d_in[31];
  const in_t* a_ln1_g = (const in_t*)d_in[32]; const in_t* a_ln1_b = (const in_t*)d_in[33];
  const in_t* a_qkv_w = (const in_t*)d_in[34]; const in_t* a_qkv_b = (const in_t*)d_in[35];
  const in_t* a_prj_w = (const in_t*)d_in[36]; const in_t* a_prj_b = (const in_t*)d_in[37];
  const in_t* a_ln2_g = (const in_t*)d_in[38]; const in_t* a_ln2_b = (const in_t*)d_in[39];
  const in_t* a_fc1_w = (const in_t*)d_in[40]; const in_t* a_fc1_b = (const in_t*)d_in[41];
  const in_t* a_fc2_w = (const in_t*)d_in[42]; const in_t* a_fc2_b = (const in_t*)d_in[43];
  const in_t* final_g = (const in_t*)d_in[44]; const in_t* final_b = (const in_t*)d_in[45];
  const in_t* h1_w = (const in_t*)d_in[46];    const in_t* h1_b = (const in_t*)d_in[47];
  const in_t* h2_w = (const in_t*)d_in[48];    const in_t* h2_b = (const in_t*)d_in[49];

  float* ws = (float*)d_ws;
  size_t off = 0;
  auto alloc = [&](size_t nf) { size_t r = off; off += (nf + 63) & ~((size_t)63); return r; };
  size_t oX   = alloc((size_t)ROWS_*DMODEL);
  size_t oX2  = alloc((size_t)ROWS_*DMODEL);
  size_t oH   = alloc((size_t)ROWS_*DMODEL);
  size_t oQKV = alloc((size_t)ROWS_*1152);
  size_t oY   = alloc((size_t)ROWS_*384);
  size_t oFF  = alloc((size_t)ROWS_*768);
  size_t oA0  = alloc((size_t)480*NTOK);
  size_t oSB  = alloc((size_t)BT_*196);
  size_t oXC  = alloc((size_t)16*6*DMODEL);
  size_t oIDX = alloc((size_t)BT_*NTOK);
  size_t oWB  = alloc((size_t)4202496 + 64);   // 8.4M bf16 weights
  if (ws_size < off*sizeof(float)) return;

  float* X   = ws + oX;
  float* X2  = ws + oX2;
  float* H   = ws + oH;
  float* QKV = ws + oQKV;
  float* Y   = ws + oY;
  float* FF  = ws + oFF;
  float* A0  = ws + oA0;
  float* SB  = ws + oSB;
  float* XC  = ws + oXC;
  int*   IDX = (int*)(ws + oIDX);
  short* WB  = (short*)(ws + oWB);

  // bf16 weight slots (in shorts), layout [L][N][K]
  size_t wo = 0;
  auto wslot = [&](size_t n){ size_t r = wo; wo += n; return r; };
  size_t wPatch = wslot(147456);
  size_t wSqkv  = wslot(442368);
  size_t wSout  = wslot(147456);
  size_t wSfc1  = wslot(294912);
  size_t wSfc2  = wslot(294912);
  size_t wAqkv  = wslot(1327104);
  size_t wAprj  = wslot(442368);
  size_t wAfc1  = wslot(1769472);
  size_t wAfc2  = wslot(1769472);
  size_t wTqkv  = wslot(663552);
  size_t wTout  = wslot(221184);
  size_t wTfc1  = wslot(442368);
  size_t wTfc2  = wslot(442368);

  auto wconv = [&](const in_t* W, size_t slot, int K, int N, int L) {
    dim3 g(N/32, K/32, L);
    hipLaunchKernelGGL(wconv_k, g, dim3(256), 0, stream, W, WB + slot, K, N);
  };
  wconv(patch_w, wPatch, 768, 192, 1);
  wconv(s_qkv_w, wSqkv, 192, 1152, 2);
  wconv(s_out_w, wSout, 384, 192, 2);
  wconv(s_fc1_w, wSfc1, 192, 768, 2);
  wconv(s_fc2_w, wSfc2, 768, 192, 2);
  wconv(a_qkv_w, wAqkv, 192, 576, 12);
  wconv(a_prj_w, wAprj, 192, 192, 12);
  wconv(a_fc1_w, wAfc1, 192, 768, 12);
  wconv(a_fc2_w, wAfc2, 768, 192, 12);
  wconv(t_qkv_w, wTqkv, 192, 1152, 3);
  wconv(t_out_w, wTout, 384, 192, 3);
  wconv(t_fc1_w, wTfc1, 192, 768, 3);
  wconv(t_fc2_w, wTfc2, 768, 192, 3);

  auto gemm = [&](int epi, const float* A, const short* Wt, const in_t* bias,
                  const float* R, float* C, int M, int N, int K) {
    dim3 grid(N/64, (M+63)/64);
    if (epi == 0)      hipLaunchKernelGGL(gemmM_k<0>, grid, dim3(256), 0, stream, A, Wt, bias, R, C, M, N, K);
    else if (epi == 1) hipLaunchKernelGGL(gemmM_k<1>, grid, dim3(256), 0, stream, A, Wt, bias, R, C, M, N, K);
    else               hipLaunchKernelGGL(gemmM_k<2>, grid, dim3(256), 0, stream, A, Wt, bias, R, C, M, N, K);
  };
  auto ln = [&](const float* xi, const in_t* g, const in_t* b, float* o, int rows) {
    hipLaunchKernelGGL(ln_k, dim3((rows+3)/4), dim3(256), 0, stream, xi, g, b, o, rows);
  };

  // ---- 1. patch embedding ----
  {
    int total = BT_*196*768;
    hipLaunchKernelGGL(patchify_k, dim3((total+255)/256), dim3(256), 0, stream, x_in, FF);
    gemm(0, FF, WB + wPatch, patch_b, nullptr, Y, BT_*196, DMODEL, 768);
    int tot2 = BT_*NTOK*DMODEL;
    hipLaunchKernelGGL(assemble_k, dim3((tot2+255)/256), dim3(256), 0, stream, Y, space_tk, pos_emb, X);
  }

  const float sc64 = 0.125f;
  const float sc32 = 0.17677669529663687f;

  // ---- 2. spatial transformer (2 layers, heads=6, dh=64) ----
  for (int i = 0; i < 2; ++i) {
    ln(X, s_ln1_g + (size_t)i*192, s_ln1_b + (size_t)i*192, H, ROWS_);
    gemm(0, H, WB + wSqkv + (size_t)i*192*1152, nullptr, nullptr, QKV, ROWS_, 1152, 192);
    hipLaunchKernelGGL((attn2r_k<64,8>), dim3(BT_*6), dim3(512), 0, stream, QKV, Y, (float*)nullptr, NTOK, 6, sc64);
    gemm(2, Y, WB + wSout + (size_t)i*384*192, s_out_b + (size_t)i*192, X, X, ROWS_, 192, 384);
    ln(X, s_ln2_g + (size_t)i*192, s_ln2_b + (size_t)i*192, H, ROWS_);
    gemm(1, H, WB + wSfc1 + (size_t)i*192*768, s_fc1_b + (size_t)i*768, nullptr, FF, ROWS_, 768, 192);
    gemm(2, FF, WB + wSfc2 + (size_t)i*768*192, s_fc2_b + (size_t)i*192, X, X, ROWS_, 192, 768);
  }
  ln(X, s_nrm_g, s_nrm_b, X, ROWS_);

  // ---- 3. ATS blocks (12 layers, heads=6, dh=32) ----
  float* xa = X; float* xb = X2;
  for (int i = 0; i < 12; ++i) {
    ln(xa, a_ln1_g + (size_t)i*192, a_ln1_b + (size_t)i*192, H, ROWS_);
    gemm(0, H, WB + wAqkv + (size_t)i*192*576, a_qkv_b + (size_t)i*576, nullptr, QKV, ROWS_, 576, 192);
    hipLaunchKernelGGL((attn2r_k<32,4>), dim3(BT_*6), dim3(256), 0, stream, QKV, Y, A0, NTOK, 6, sc32);
    gemm(0, Y, WB + wAprj + (size_t)i*192*192, a_prj_b + (size_t)i*192, nullptr, H, ROWS_, 192, 192);
    hipLaunchKernelGGL(score_k, dim3(BT_), dim3(256), 0, stream, A0, QKV, SB);
    hipLaunchKernelGGL(sample_k, dim3(BT_), dim3(256), 0, stream, SB, IDX);
    {
      int tot = BT_*NTOK*DMODEL;
      hipLaunchKernelGGL(gather_k, dim3((tot+255)/256), dim3(256), 0, stream, xa, H, IDX, xb);
    }
    ln(xb, a_ln2_g + (size_t)i*192, a_ln2_b + (size_t)i*192, H, ROWS_);
    gemm(1, H, WB + wAfc1 + (size_t)i*192*768, a_fc1_b + (size_t)i*768, nullptr, FF, ROWS_, 768, 192);
    gemm(2, FF, WB + wAfc2 + (size_t)i*768*192, a_fc2_b + (size_t)i*192, xb, xb, ROWS_, 192, 768);
    float* tmp = xa; xa = xb; xb = tmp;
  }

  // ---- 4. temporal transformer (3 layers on [16,6,192]) ----
  {
    int tot = 16*6*DMODEL;
    hipLaunchKernelGGL(build_xc_k, dim3((tot+255)/256), dim3(256), 0, stream, xa, temp_tk, XC);
  }
  const int MT = 16*6;
  for (int i = 0; i < 3; ++i) {
    ln(XC, t_ln1_g + (size_t)i*192, t_ln1_b + (size_t)i*192, H, MT);
    gemm(0, H, WB + wTqkv + (size_t)i*192*1152, nullptr, nullptr, QKV, MT, 1152, 192);
    hipLaunchKernelGGL((attn2r_k<64,8>), dim3(16*6), dim3(512), 0, stream, QKV, Y, (float*)nullptr, 6, 6, sc64);
    gemm(2, Y, WB + wTout + (size_t)i*384*192, t_out_b + (size_t)i*192, XC, XC, MT, 192, 384);
    ln(XC, t_ln2_g + (size_t)i*192, t_ln2_b + (size_t)i*192, H, MT);
    gemm(1, H, WB + wTfc1 + (size_t)i*192*768, t_fc1_b + (size_t)i*768, nullptr, FF, MT, 768, 192);
    gemm(2, FF, WB + wTfc2 + (size_t)i*768*192, t_fc2_b + (size_t)i*192, XC, XC, MT, 192, 768);
  }
  ln(XC, t_nrm_g, t_nrm_b, XC, MT);

  // ---- 5. maxpool + final LN + head ----
  hipLaunchKernelGGL(head_k, dim3(16), dim3(256), 0, stream, XC, final_g, final_b,
                     h1_w, h1_b, h2_w, h2_b, (out_t*)d_out);
}